// Round 1
// baseline (412.058 us; speedup 1.0000x reference)
//
#include <hip/hip_runtime.h>
#include <math.h>

#define B_ 1024
#define T_ 512
#define K_ 48

// One 64-lane wave per batch element. Lanes 0..47 own state j.
// E (=exp(transitions)) columns live in registers; e-vector broadcast via
// v_readlane (no LDS, no barriers in the hot loop).
__global__ __launch_bounds__(64) void crf_main(
    const float* __restrict__ emissions,
    const int*   __restrict__ tags,
    const float* __restrict__ mask,
    const float* __restrict__ transitions,
    const float* __restrict__ start_t,
    const float* __restrict__ end_t,
    float* __restrict__ partial)
{
    const int b    = blockIdx.x;
    const int lane = threadIdx.x;
    const bool act = lane < K_;

    const int*   tb = tags + b * T_;
    const float* mb = mask + b * T_;
    const float* eb = emissions + (size_t)b * T_ * K_;

    // ---- E columns in registers: Ecol[i] = exp(transitions[i][lane]) ----
    float Ecol[K_];
    #pragma unroll
    for (int i = 0; i < K_; ++i)
        Ecol[i] = act ? __expf(transitions[i * K_ + lane]) : 0.f;

    // ---- phase A: numerator (score_sentence), lanes parallel over t ----
    float acc = 0.f, msum = 0.f;
    for (int t = lane; t < T_ - 1; t += 64) {
        int t0 = tb[t], t1 = tb[t + 1];
        acc += eb[t * K_ + t0] + transitions[t0 * K_ + t1] * mb[t + 1];
    }
    for (int t = lane; t < T_; t += 64) msum += mb[t];
    #pragma unroll
    for (int off = 32; off; off >>= 1) {
        acc  += __shfl_xor(acc, off);
        msum += __shfl_xor(msum, off);
    }
    // uniform across lanes now
    int   last_idx = (int)(msum + 0.5f) - 1;
    float log_num  = start_t[tb[0]] + acc + end_t[tb[last_idx]];

    // ---- phase B: forward recurrence ----
    float alpha = act ? (start_t[lane] + eb[lane]) : -INFINITY;

    // 4-deep emissions prefetch (covers ~900cy HBM latency)
    float pf0 = (act && 1 < T_) ? eb[1 * K_ + lane] : 0.f;
    float pf1 = (act && 2 < T_) ? eb[2 * K_ + lane] : 0.f;
    float pf2 = (act && 3 < T_) ? eb[3 * K_ + lane] : 0.f;
    float pf3 = (act && 4 < T_) ? eb[4 * K_ + lane] : 0.f;

    #pragma unroll 4
    for (int t = 1; t < T_; ++t) {
        float emit = pf0;
        pf0 = pf1; pf1 = pf2; pf2 = pf3;
        int tn = t + 4;
        pf3 = (act && tn < T_) ? eb[tn * K_ + lane] : 0.f;

        float mt = mb[t];
        float v  = alpha + emit;              // -inf on inactive lanes

        // wave max (lanes 48..63 contribute -inf)
        float m = v;
        #pragma unroll
        for (int off = 32; off; off >>= 1) m = fmaxf(m, __shfl_xor(m, off));

        float e = __expf(v - m);              // 0 on inactive lanes (m finite)

        // dot: s = sum_i e[i] * Ecol[i]  via readlane broadcast
        float s0 = 0.f, s1 = 0.f, s2 = 0.f, s3 = 0.f;
        #pragma unroll
        for (int i = 0; i < K_; i += 4) {
            float e0 = __uint_as_float(__builtin_amdgcn_readlane(__float_as_uint(e), i + 0));
            float e1 = __uint_as_float(__builtin_amdgcn_readlane(__float_as_uint(e), i + 1));
            float e2 = __uint_as_float(__builtin_amdgcn_readlane(__float_as_uint(e), i + 2));
            float e3 = __uint_as_float(__builtin_amdgcn_readlane(__float_as_uint(e), i + 3));
            s0 = fmaf(e0, Ecol[i + 0], s0);
            s1 = fmaf(e1, Ecol[i + 1], s1);
            s2 = fmaf(e2, Ecol[i + 2], s2);
            s3 = fmaf(e3, Ecol[i + 3], s3);
        }
        float s = (s0 + s1) + (s2 + s3);

        float anew = (m + __logf(s)) * mt;    // ref: logsumexp(...) * mask_t
        alpha = act ? anew : -INFINITY;
    }

    // ---- final logsumexp(alpha + end) ----
    float v2 = act ? (alpha + end_t[lane]) : -INFINITY;
    float m2 = v2;
    #pragma unroll
    for (int off = 32; off; off >>= 1) m2 = fmaxf(m2, __shfl_xor(m2, off));
    float e2 = __expf(v2 - m2);
    #pragma unroll
    for (int off = 32; off; off >>= 1) e2 += __shfl_xor(e2, off);

    if (lane == 0) {
        float log_den = m2 + __logf(e2);
        partial[b] = log_den - log_num;
    }
}

__global__ __launch_bounds__(256) void crf_reduce(const float* __restrict__ partial,
                                                  float* __restrict__ out)
{
    __shared__ float sh[4];
    const int l = threadIdx.x;
    float s = 0.f;
    for (int i = l; i < B_; i += 256) s += partial[i];
    #pragma unroll
    for (int off = 32; off; off >>= 1) s += __shfl_xor(s, off);
    if ((l & 63) == 0) sh[l >> 6] = s;
    __syncthreads();
    if (l == 0) out[0] = (sh[0] + sh[1] + sh[2] + sh[3]) / (float)B_;
}

extern "C" void kernel_launch(void* const* d_in, const int* in_sizes, int n_in,
                              void* d_out, int out_size, void* d_ws, size_t ws_size,
                              hipStream_t stream) {
    const float* emissions   = (const float*)d_in[0];
    const int*   tags        = (const int*)  d_in[1];
    const float* mask        = (const float*)d_in[2];
    const float* transitions = (const float*)d_in[3];
    const float* start_t     = (const float*)d_in[4];
    const float* end_t       = (const float*)d_in[5];
    float* out     = (float*)d_out;
    float* partial = (float*)d_ws;

    crf_main<<<B_, 64, 0, stream>>>(emissions, tags, mask, transitions,
                                    start_t, end_t, partial);
    crf_reduce<<<1, 256, 0, stream>>>(partial, out);
}

// Round 11
// 253.719 us; speedup vs baseline: 1.6241x; 1.6241x over previous
//
#include <hip/hip_runtime.h>
#include <math.h>

#define B_ 1024
#define T_ 512
#define K_ 48

typedef _Float16 h2 __attribute__((ext_vector_type(2)));

__device__ __forceinline__ float readlane_f(float v, int lane) {
    return __uint_as_float(__builtin_amdgcn_readlane(__float_as_uint(v), lane));
}
__device__ __forceinline__ h2 bits_to_h2(int b) {
    union { int i; h2 h; } u; u.i = b; return u.h;
}
// cvt_pkrtz returns __fp16x2 on this toolchain; bit-identical to h2.
__device__ __forceinline__ h2 cvt_pk(float a, float b) {
    return __builtin_bit_cast(h2, __builtin_amdgcn_cvt_pkrtz(a, b));
}

// One 64-lane wave per batch element. Lanes 0..47 own state j.
// Recurrence runs in NORMALIZED LINEAR domain: alpha_full_j = 2^Ct * alpha_j.
// Per step: e_i = alpha_i * p_i (p = 2^(emit*log2e), precomputed 8 steps early
// in the prefetch pipeline), s_j = sum_i e_i*E_ij via packed-f16 dot2, then
// renorm by lane0: alpha' = s * rcp(s_0), Ct += log2(s_0) (side chain).
// No exp/log/max-reduce on the critical path; no +-inf in the hot loop.
__global__ __launch_bounds__(64) void crf_main(
    const float* __restrict__ emissions,
    const int*   __restrict__ tags,
    const float* __restrict__ mask,
    const float* __restrict__ transitions,
    const float* __restrict__ start_t,
    const float* __restrict__ end_t,
    float* __restrict__ partial)
{
    const int b    = blockIdx.x;
    const int lane = threadIdx.x;
    const bool act = lane < K_;

    const int*   tb = tags + b * T_;
    const float* mb = mask + b * T_;
    const float* eb = emissions + (size_t)b * T_ * K_;

    const float LOG2E = 1.4426950408889634f;
    const float LN2   = 0.6931471805599453f;

    // ---- E pairs in registers: Ep[k] = f16x2( exp(T[2k][lane]), exp(T[2k+1][lane]) )
    h2 Ep[24];
    #pragma unroll
    for (int k = 0; k < 24; ++k) {
        float a0 = act ? __expf(transitions[(2*k)   * K_ + lane]) : 0.f;
        float a1 = act ? __expf(transitions[(2*k+1) * K_ + lane]) : 0.f;
        Ep[k] = cvt_pk(a0, a1);
    }

    // ---- phase A: numerator (score_sentence), lanes parallel over t ----
    float acc = 0.f, msum = 0.f;
    for (int t = lane; t < T_ - 1; t += 64) {
        int t0 = tb[t], t1 = tb[t + 1];
        acc += eb[t * K_ + t0] + transitions[t0 * K_ + t1] * mb[t + 1];
    }
    for (int t = lane; t < T_; t += 64) msum += mb[t];
    #pragma unroll
    for (int off = 32; off; off >>= 1) {
        acc  += __shfl_xor(acc, off);
        msum += __shfl_xor(msum, off);
    }
    int   last_idx = (int)(msum + 0.5f) - 1;
    float log_num  = start_t[tb[0]] + acc + end_t[tb[last_idx]];

    // ---- phase B init: one-time max-anchored normalization ----
    float a0log = act ? (start_t[lane] + eb[lane]) * LOG2E : -INFINITY;
    float m0 = a0log;
    #pragma unroll
    for (int off = 32; off; off >>= 1) m0 = fmaxf(m0, __shfl_xor(m0, off));
    float alpha = act ? __builtin_amdgcn_exp2f(a0log - m0) : 0.f;  // <= 1
    float Ct    = m0;

    const float* epf = eb + (act ? lane : 0);

    // 8-deep prefetch: p = 2^(emit*log2e) computed at slot-fill (off chain)
    float pp0 = __builtin_amdgcn_exp2f(epf[1 * K_] * LOG2E);
    float pp1 = __builtin_amdgcn_exp2f(epf[2 * K_] * LOG2E);
    float pp2 = __builtin_amdgcn_exp2f(epf[3 * K_] * LOG2E);
    float pp3 = __builtin_amdgcn_exp2f(epf[4 * K_] * LOG2E);
    float pp4 = __builtin_amdgcn_exp2f(epf[5 * K_] * LOG2E);
    float pp5 = __builtin_amdgcn_exp2f(epf[6 * K_] * LOG2E);
    float pp6 = __builtin_amdgcn_exp2f(epf[7 * K_] * LOG2E);
    float pp7 = __builtin_amdgcn_exp2f(epf[8 * K_] * LOG2E);
    float pm0 = mb[1], pm1 = mb[2], pm2 = mb[3], pm3 = mb[4];
    float pm4 = mb[5], pm5 = mb[6], pm6 = mb[7], pm7 = mb[8];

    #pragma unroll 8
    for (int t = 1; t < T_; ++t) {
        float p  = pp0; pp0 = pp1; pp1 = pp2; pp2 = pp3; pp3 = pp4;
                        pp4 = pp5; pp5 = pp6; pp6 = pp7;
        float mt = pm0; pm0 = pm1; pm1 = pm2; pm2 = pm3; pm3 = pm4;
                        pm4 = pm5; pm5 = pm6; pm6 = pm7;
        int tn = t + 8;
        int tc = tn < T_ ? tn : T_ - 1;       // clamped (tail loads are dummies)
        pp7 = __builtin_amdgcn_exp2f(epf[tc * K_] * LOG2E);
        pm7 = mb[tc];

        // e_i = alpha_i * p_i  (inactive lanes: 0). cvt_pkrtz is RTZ ->
        // saturates overflow to 65504 (no f16 inf); rare-tail clamp error
        // is negligible on the 1024-batch mean.
        float e  = alpha * p;
        int   en = __builtin_amdgcn_update_dpp(0, __float_as_int(e), 0xB1, 0xF, 0xF, true);
        h2    pk = cvt_pk(e, __int_as_float(en));
        int  pkb = __builtin_bit_cast(int, pk);

        // s_j = sum_i e_i*E_ij : 24 readlane pair-broadcasts, 6 dot2 chains
        float s0 = 0.f, s1 = 0.f, s2 = 0.f, s3 = 0.f, s4 = 0.f, s5 = 0.f;
        #pragma unroll
        for (int k = 0; k < 24; k += 6) {
            int b0 = __builtin_amdgcn_readlane(pkb, 2 * (k + 0));
            int b1 = __builtin_amdgcn_readlane(pkb, 2 * (k + 1));
            int b2 = __builtin_amdgcn_readlane(pkb, 2 * (k + 2));
            int b3 = __builtin_amdgcn_readlane(pkb, 2 * (k + 3));
            int b4 = __builtin_amdgcn_readlane(pkb, 2 * (k + 4));
            int b5 = __builtin_amdgcn_readlane(pkb, 2 * (k + 5));
            s0 = __builtin_amdgcn_fdot2(Ep[k + 0], bits_to_h2(b0), s0, false);
            s1 = __builtin_amdgcn_fdot2(Ep[k + 1], bits_to_h2(b1), s1, false);
            s2 = __builtin_amdgcn_fdot2(Ep[k + 2], bits_to_h2(b2), s2, false);
            s3 = __builtin_amdgcn_fdot2(Ep[k + 3], bits_to_h2(b3), s3, false);
            s4 = __builtin_amdgcn_fdot2(Ep[k + 4], bits_to_h2(b4), s4, false);
            s5 = __builtin_amdgcn_fdot2(Ep[k + 5], bits_to_h2(b5), s5, false);
        }
        float s = ((s0 + s1) + (s2 + s3)) + (s4 + s5);

        // renorm by lane0's s (always > 0: alpha_0 contributes e_0*E_00 > 0)
        float c    = readlane_f(s, 0);
        float rn   = __builtin_amdgcn_rcpf(c);
        float anew = s * rn;
        // mask fold: ref alpha' = lse * mt  ->  linear: alpha'=1, Ct=0 when mt==0
        alpha = (mt != 0.0f) ? anew : 1.0f;
        Ct    = (Ct + __builtin_amdgcn_logf(c)) * mt;   // side chain (log2)
    }

    // ---- final: log_den = (Ct + log2( sum_j alpha_j * 2^(end_j*log2e) )) * ln2
    float vfin = act ? alpha * __builtin_amdgcn_exp2f(end_t[lane] * LOG2E) : 0.f;
    #pragma unroll
    for (int off = 32; off; off >>= 1) vfin += __shfl_xor(vfin, off);

    if (lane == 0) {
        float log_den = (Ct + __builtin_amdgcn_logf(vfin)) * LN2;
        partial[b] = log_den - log_num;
    }
}

__global__ __launch_bounds__(256) void crf_reduce(const float* __restrict__ partial,
                                                  float* __restrict__ out)
{
    __shared__ float sh[4];
    const int l = threadIdx.x;
    float s = 0.f;
    for (int i = l; i < B_; i += 256) s += partial[i];
    #pragma unroll
    for (int off = 32; off; off >>= 1) s += __shfl_xor(s, off);
    if ((l & 63) == 0) sh[l >> 6] = s;
    __syncthreads();
    if (l == 0) out[0] = (sh[0] + sh[1] + sh[2] + sh[3]) / (float)B_;
}

extern "C" void kernel_launch(void* const* d_in, const int* in_sizes, int n_in,
                              void* d_out, int out_size, void* d_ws, size_t ws_size,
                              hipStream_t stream) {
    const float* emissions   = (const float*)d_in[0];
    const int*   tags        = (const int*)  d_in[1];
    const float* mask        = (const float*)d_in[2];
    const float* transitions = (const float*)d_in[3];
    const float* start_t     = (const float*)d_in[4];
    const float* end_t       = (const float*)d_in[5];
    float* out     = (float*)d_out;
    float* partial = (float*)d_ws;

    crf_main<<<B_, 64, 0, stream>>>(emissions, tags, mask, transitions,
                                    start_t, end_t, partial);
    crf_reduce<<<1, 256, 0, stream>>>(partial, out);
}